// Round 11
// baseline (28.654 us; speedup 1.0000x reference)
//
#include <hip/hip_runtime.h>
#include <hip/hip_fp16.h>

// HalutMatmul forward on MI355X.
// Per row n: h[c][p] = sum_d I[n, c*9+d] * A[c][d][p]   (c=0..15, p=0..3)
//            code_c  = 4-level tree descent: bit_l = (h[c][l] > T[c*15 + node_l])
//            out[n][m] = sum_c L[m][c][code_c]
//
// Round-11: VALU attack on round-10 (27.4us). Pipe ledger: VALU was the
// tallest pillar (~15us/CU), dominated by the f64 hash (v_fma_f64 = half
// rate). Hash now runs in packed f32 (v_pk_fma_f32) with a +-1e-3 borderline
// guard; guarded-safe decisions provably equal the f64 ones (f32 err <=2e-5),
// borderline cases (~500 chip-wide) take a predicated f64 recompute in the
// EXACT f64 FMA order of rounds 1-10 -> codes bit-identical, absmax 0.0039.
// Everything else (role-switch hash, f16 LUT gather, swizzled epilogue) is
// round-10 verbatim.

#define NROWS (1024 * 128)

typedef __attribute__((ext_vector_type(2))) float f32x2;

__global__ __launch_bounds__(256, 2) void halut_fwd(
    const float* __restrict__ I,
    const float* __restrict__ A,
    const float* __restrict__ T,
    const float* __restrict__ L,
    float* __restrict__ out)
{
    // 32KB f16 LUT (reused as epilogue staging) + 4x9KB per-wave I tiles + 4KB codes
    __shared__ uint32_t sLut[8192];
    __shared__ float    sStage[4][2304];   // wave-private: 16 rows x 144 f32
    __shared__ uint8_t  sCodes[4096];      // [256 block-rows][16 c]

    const int tid  = threadIdx.x;
    const int w    = tid >> 6;
    const int lane = tid & 63;

    // ---- per-lane constants: lane (g,c) owns codebook cB ----
    const int cB = lane & 15;              // codebook (hash phase)
    const int g  = lane >> 4;              // row-in-pass (hash phase)
    f32x2 a01[9], a23[9];
    {
        const float4* ap4 = (const float4*)(A + cB * 36);   // 144B-aligned
        #pragma unroll
        for (int i = 0; i < 9; ++i) {
            const float4 v = ap4[i];
            a01[i] = (f32x2){v.x, v.y};
            a23[i] = (f32x2){v.z, v.w};
        }
    }
    float Tf[15];
    #pragma unroll
    for (int j = 0; j < 15; ++j) Tf[j] = T[cB * 15 + j];

    // ---- stage f16 LUT: thread t owns column col = t (round-8 layout) ----
    {
        uint4* lut4 = (uint4*)sLut;
        #pragma unroll
        for (int q = 0; q < 8; ++q) {
            uint32_t wv[4];
            #pragma unroll
            for (int e = 0; e < 4; ++e) {
                const float fa = L[(8*q + 2*e)     * 256 + tid];
                const float fb = L[(8*q + 2*e + 1) * 256 + tid];
                wv[e] = ((uint32_t)__half_as_ushort(__float2half_rn(fb)) << 16)
                      |  (uint32_t)__half_as_ushort(__float2half_rn(fa));
            }
            lut4[q * 256 + tid] = make_uint4(wv[0], wv[1], wv[2], wv[3]);
        }
    }
    __syncthreads();   // only cross-wave dependency: LUT visible to all waves

    // ---- hash superphases: 4 x (stage 16 rows coalesced, 4 passes x 4 rows) ----
    const int wave_row0 = blockIdx.x * 256 + w * 64;   // global row base of wave
    const float4* Isrc = (const float4*)I;
    float4* st4 = (float4*)sStage[w];

    float4 nbuf[9];
    #pragma unroll
    for (int i = 0; i < 9; ++i)
        nbuf[i] = Isrc[(size_t)wave_row0 * 36 + i * 64 + lane];

    // node j sits at tree level lvl[j]; decision uses h[lvl[j]]
    const int lvl[15] = {0, 1,1, 2,2,2,2, 3,3,3,3,3,3,3,3};

    #pragma unroll
    for (int p16 = 0; p16 < 4; ++p16) {
        #pragma unroll
        for (int i = 0; i < 9; ++i) st4[i * 64 + lane] = nbuf[i];   // write-late
        if (p16 < 3) {                                               // issue-early
            #pragma unroll
            for (int i = 0; i < 9; ++i)
                nbuf[i] = Isrc[(size_t)(wave_row0 + (p16+1)*16) * 36 + i*64 + lane];
        }
        #pragma unroll
        for (int ps = 0; ps < 4; ++ps) {
            const int lr = ps * 4 + g;            // row 0..15 within chunk
            const float* xr = &sStage[w][lr * 144 + cB * 9];

            // ---- packed f32 hash (v_pk_fma_f32), keep xs for fallback ----
            float xv[9];
            f32x2 h01 = (f32x2){0.f, 0.f}, h23 = (f32x2){0.f, 0.f};
            #pragma unroll
            for (int d = 0; d < 9; ++d) {
                const float x = xr[d];
                xv[d] = x;
                const f32x2 xx = (f32x2){x, x};
                h01 = __builtin_elementwise_fma(xx, a01[d], h01);
                h23 = __builtin_elementwise_fma(xx, a23[d], h23);
            }
            const float hh[4] = {h01.x, h01.y, h23.x, h23.y};

            uint32_t mk = 0, bl = 0;
            #pragma unroll
            for (int j = 0; j < 15; ++j) {
                const float b = hh[lvl[j]] - Tf[j];
                mk |= (b > 0.f) ? (1u << j) : 0u;
                bl |= (fabsf(b) < 1e-3f) ? 1u : 0u;
            }
            if (bl) {   // rare (~500 decisions chip-wide): exact f64, same
                        // FMA order as rounds 1-10 -> codes bit-identical
                double h0 = 0.0, h1 = 0.0, h2 = 0.0, h3 = 0.0;
                #pragma unroll
                for (int d = 0; d < 9; ++d) {
                    const double x = (double)xv[d];
                    h0 = fma(x, (double)a01[d].x, h0);
                    h1 = fma(x, (double)a01[d].y, h1);
                    h2 = fma(x, (double)a23[d].x, h2);
                    h3 = fma(x, (double)a23[d].y, h3);
                }
                const double hd[4] = {h0, h1, h2, h3};
                mk = 0;
                #pragma unroll
                for (int j = 0; j < 15; ++j)
                    mk |= (hd[lvl[j]] > (double)Tf[j]) ? (1u << j) : 0u;
            }
            int p =       (int)(mk & 1u);
            p = 2 * p + (int)((mk >> (1 + p)) & 1u);
            p = 2 * p + (int)((mk >> (3 + p)) & 1u);
            p = 2 * p + (int)((mk >> (7 + p)) & 1u);
            sCodes[(w * 64 + p16 * 16 + lr) * 16 + cB] = (uint8_t)p;
        }
    }

    // ---- gather: lane = row (round-8/10 proven path) ----
    const uint4 cw = *(const uint4*)&sCodes[tid * 16];   // my row's 16 codes
    const uint32_t cd0 = cw.x, cd1 = cw.y, cd2 = cw.z, cd3 = cw.w;

    __half2 acc2[32];
    #pragma unroll
    for (int k = 0; k < 32; ++k) acc2[k] = __floats2half2_rn(0.f, 0.f);

    const uint4* lut4 = (const uint4*)sLut;
    #pragma unroll 4
    for (int c = 0; c < 16; ++c) {
        const uint32_t cdw = (c < 4) ? cd0 : (c < 8) ? cd1 : (c < 12) ? cd2 : cd3;
        const int p = (int)((cdw >> ((c & 3) * 8)) & 15u);
        const uint4* colp = lut4 + (c << 4) + p;
        #pragma unroll
        for (int q = 0; q < 8; ++q) {
            const uint4 wv = colp[q << 8];
            acc2[q*4+0] = __hadd2(acc2[q*4+0], *(const __half2*)&wv.x);
            acc2[q*4+1] = __hadd2(acc2[q*4+1], *(const __half2*)&wv.y);
            acc2[q*4+2] = __hadd2(acc2[q*4+2], *(const __half2*)&wv.z);
            acc2[q*4+3] = __hadd2(acc2[q*4+3], *(const __half2*)&wv.w);
        }
    }

    // ---- epilogue: swizzled LDS transpose (round-8/10 verbatim), 2x128 rows ----
    __syncthreads();                     // all gathers done; LUT region dead
    float* sO = (float*)sLut;            // [128 rows][64 m], 16B-chunk swizzle
    #pragma unroll
    for (int half = 0; half < 2; ++half) {
        if ((tid >> 7) == half) {        // wave-uniform branch
            const int r = tid & 127;
            #pragma unroll
            for (int ch = 0; ch < 16; ++ch) {
                const float4 v = make_float4(__low2float (acc2[2 * ch]),
                                             __high2float(acc2[2 * ch]),
                                             __low2float (acc2[2 * ch + 1]),
                                             __high2float(acc2[2 * ch + 1]));
                *(float4*)&sO[(r << 6) + ((ch ^ (r & 15)) << 2)] = v;
            }
        }
        __syncthreads();
        float4* op = (float4*)(out + (size_t)blockIdx.x * (256 * 64)
                                   + (size_t)half * (128 * 64));
        #pragma unroll
        for (int j = 0; j < 8; ++j) {    // 2048 float4 = 32 KiB, contiguous
            const int F  = tid + (j << 8);
            const int r2 = F >> 4;
            const int m2 = F & 15;
            op[F] = *(const float4*)&sO[(r2 << 6) + ((m2 ^ (r2 & 15)) << 2)];
        }
        __syncthreads();
    }
}

extern "C" void kernel_launch(void* const* d_in, const int* in_sizes, int n_in,
                              void* d_out, int out_size, void* d_ws, size_t ws_size,
                              hipStream_t stream) {
    const float* I = (const float*)d_in[0];
    const float* A = (const float*)d_in[1];
    const float* T = (const float*)d_in[2];
    const float* L = (const float*)d_in[3];
    float* outp = (float*)d_out;

    const int nblocks = NROWS / 256;   // 512 blocks x 256 threads
    halut_fwd<<<nblocks, 256, 0, stream>>>(I, A, T, L, outp);
}